// Round 3
// baseline (346.752 us; speedup 1.0000x reference)
//
#include <hip/hip_runtime.h>
#include <hip/hip_bf16.h>

#define NSEQ 256   // N_SEQ (attention axis)
#define NRES 384   // N_RES
#define CM   256   // C_M
#define NH   8
#define HC   32    // head dim

typedef __bf16 bf16x8_t __attribute__((ext_vector_type(8)));
typedef __bf16 bf16x4_t __attribute__((ext_vector_type(4)));
typedef float  f32x4_t  __attribute__((ext_vector_type(4)));
typedef unsigned int u32x4_t __attribute__((ext_vector_type(4)));

static __device__ __forceinline__ f32x4_t mfma16(bf16x8_t a, bf16x8_t b, f32x4_t c) {
    return __builtin_amdgcn_mfma_f32_16x16x32_bf16(a, b, c, 0, 0, 0);
}

static __device__ __forceinline__ bf16x4_t to_bf4(f32x4_t v) {
    bf16x4_t o;
    o[0] = (__bf16)v[0]; o[1] = (__bf16)v[1];
    o[2] = (__bf16)v[2]; o[3] = (__bf16)v[3];
    return o;
}

static __device__ __forceinline__ unsigned int pkbf(float a, float b) {
    union { __bf16 h[2]; unsigned int u; } t;
    t.h[0] = (__bf16)a; t.h[1] = (__bf16)b;
    return t.u;
}

// swizzled kq buffer addressing: [256 rows][64 elems] as 8 chunks of 8 elems,
// chunk' = chunk ^ (row&7).  k in chunks 0..3, q in chunks 4..7.
static __device__ __forceinline__ int kq_addr(int row, int chunk, int e) {
    return row * 64 + ((chunk ^ (row & 7)) << 3) + e;
}

// ---------------- Kernel 1: weight prep (transpose + bf16) ----------------
// wt layout: [5][256 n][256 k], wt[w][n][k] = W[w][k][n].  0=Wq 1=Wk 2=Wv 3=Wg 4=Wo
__global__ __launch_bounds__(256) void wprep_kernel(
        const float* __restrict__ wq, const float* __restrict__ wk,
        const float* __restrict__ wv, const float* __restrict__ wg,
        const float* __restrict__ wo, __bf16* __restrict__ wt) {
    const float* src;
    switch (blockIdx.y) {
        case 0: src = wq; break; case 1: src = wk; break;
        case 2: src = wv; break; case 3: src = wg; break;
        default: src = wo; break;
    }
    __bf16* dst = wt + (size_t)blockIdx.y * (CM * CM);
    int n  = blockIdx.x * 16 + (threadIdx.x >> 4);
    int k0 = (threadIdx.x & 15) * 16;
    #pragma unroll
    for (int kk = 0; kk < 16; ++kk) {
        int k = k0 + kk;
        dst[n * CM + k] = (__bf16)src[k * CM + n];
    }
}

// ---------------- Kernel 2: LayerNorm + transpose to (r,s) + bf16 ----------------
__global__ __launch_bounds__(256) void ln_kernel(
        const float* __restrict__ m, const float* __restrict__ gamma,
        const float* __restrict__ beta, __bf16* __restrict__ x) {
    int w = threadIdx.x >> 6, lane = threadIdx.x & 63;
    int row = blockIdx.x * 4 + w;                 // row = s*NRES + r
    const float4 mv = *reinterpret_cast<const float4*>(m + (size_t)row * CM + lane * 4);
    float s1 = mv.x + mv.y + mv.z + mv.w;
    float s2 = mv.x * mv.x + mv.y * mv.y + mv.z * mv.z + mv.w * mv.w;
    #pragma unroll
    for (int d = 1; d < 64; d <<= 1) {
        s1 += __shfl_xor(s1, d);
        s2 += __shfl_xor(s2, d);
    }
    float mu  = s1 * (1.0f / CM);
    float var = s2 * (1.0f / CM) - mu * mu;
    float rs  = rsqrtf(var + 1e-5f);
    const float4 gv = *reinterpret_cast<const float4*>(gamma + lane * 4);
    const float4 bv = *reinterpret_cast<const float4*>(beta + lane * 4);
    int s = row / NRES;
    int r = row - s * NRES;
    int drow = r * NSEQ + s;
    bf16x4_t o;
    o[0] = (__bf16)((mv.x - mu) * rs * gv.x + bv.x);
    o[1] = (__bf16)((mv.y - mu) * rs * gv.y + bv.y);
    o[2] = (__bf16)((mv.z - mu) * rs * gv.z + bv.z);
    o[3] = (__bf16)((mv.w - mu) * rs * gv.w + bv.w);
    *reinterpret_cast<bf16x4_t*>(x + (size_t)drow * CM + lane * 4) = o;
}

// ---------------- Kernel 3: fused QKVG-projection + attention + gating ----------------
// One block per (r, h), 4 waves; wave w owns seq rows [w*64, w*64+64).
// 2-pass Phase A (q,k then v,g; x re-read from L2) to halve accumulator regs.
// q+k share one XOR-swizzled LDS buffer; P never touches LDS (shfl exchange).
// go layout: [r][h][s][c] so each block writes one contiguous 16KB region.
__global__ __launch_bounds__(256, 3) void attn_kernel(
        const __bf16* __restrict__ x, const __bf16* __restrict__ wt,
        const float* __restrict__ bg, __bf16* __restrict__ go) {
    const int VRW = 264;  // v_sT row stride

    __shared__ __align__(16) char smem[49664];
    __bf16* kq_s = reinterpret_cast<__bf16*>(smem);           // [256][64] swizzled, 32768B
    __bf16* v_sT = reinterpret_cast<__bf16*>(smem + 32768);   // [32][264]  16896B

    int tid = threadIdx.x;
    int w = tid >> 6, lane = tid & 63;
    int l15 = lane & 15, g4 = lane >> 4;

    // XCD swizzle: dispatch XCD = bid % 8; nid groups the 8 h-blocks of one r
    // consecutively on the same XCD.
    int bid = blockIdx.x;
    int nid = (bid & 7) * 384 + (bid >> 3);
    int r = nid >> 3, h = nid & 7;

    const __bf16* xr = x + (size_t)r * NSEQ * CM;
    const f32x4_t zf = {0.0f, 0.0f, 0.0f, 0.0f};

    // ---- Phase A pass 1: q (wi=0), k (wi=1) ----
    f32x4_t acc1[2][4][2];
    #pragma unroll
    for (int wi = 0; wi < 2; ++wi)
        #pragma unroll
        for (int mt = 0; mt < 4; ++mt)
            #pragma unroll
            for (int ct = 0; ct < 2; ++ct) acc1[wi][mt][ct] = zf;
    #pragma unroll
    for (int kb = 0; kb < 8; ++kb) {
        bf16x8_t a[4];
        #pragma unroll
        for (int mt = 0; mt < 4; ++mt)
            a[mt] = *reinterpret_cast<const bf16x8_t*>(
                xr + (w * 64 + mt * 16 + l15) * CM + kb * 32 + g4 * 8);
        #pragma unroll
        for (int wi = 0; wi < 2; ++wi) {
            const __bf16* wslice = wt + (size_t)wi * (CM * CM) + (h * HC) * CM;
            bf16x8_t b[2];
            #pragma unroll
            for (int ct = 0; ct < 2; ++ct)
                b[ct] = *reinterpret_cast<const bf16x8_t*>(
                    wslice + (ct * 16 + l15) * CM + kb * 32 + g4 * 8);
            #pragma unroll
            for (int mt = 0; mt < 4; ++mt)
                #pragma unroll
                for (int ct = 0; ct < 2; ++ct)
                    acc1[wi][mt][ct] = mfma16(a[mt], b[ct], acc1[wi][mt][ct]);
        }
    }
    // scatter q (chunks 4..7) and k (chunks 0..3) through the swizzle
    #pragma unroll
    for (int mt = 0; mt < 4; ++mt)
        #pragma unroll
        for (int ct = 0; ct < 2; ++ct) {
            int cq = ct * 2 + (l15 >> 3);   // (c>>3), c = ct*16+l15
            int ce = l15 & 7;
            #pragma unroll
            for (int i = 0; i < 4; ++i) {
                int row = w * 64 + mt * 16 + g4 * 4 + i;
                kq_s[kq_addr(row, 4 + cq, ce)] = (__bf16)acc1[0][mt][ct][i];
                kq_s[kq_addr(row, cq, ce)]     = (__bf16)acc1[1][mt][ct][i];
            }
        }

    // ---- Phase A pass 2: v (wi=2), g (wi=3); x re-read from L2 ----
    f32x4_t acc2[2][4][2];
    #pragma unroll
    for (int wi = 0; wi < 2; ++wi)
        #pragma unroll
        for (int mt = 0; mt < 4; ++mt)
            #pragma unroll
            for (int ct = 0; ct < 2; ++ct) acc2[wi][mt][ct] = zf;
    #pragma unroll
    for (int kb = 0; kb < 8; ++kb) {
        bf16x8_t a[4];
        #pragma unroll
        for (int mt = 0; mt < 4; ++mt)
            a[mt] = *reinterpret_cast<const bf16x8_t*>(
                xr + (w * 64 + mt * 16 + l15) * CM + kb * 32 + g4 * 8);
        #pragma unroll
        for (int wi = 0; wi < 2; ++wi) {
            const __bf16* wslice = wt + (size_t)(wi + 2) * (CM * CM) + (h * HC) * CM;
            bf16x8_t b[2];
            #pragma unroll
            for (int ct = 0; ct < 2; ++ct)
                b[ct] = *reinterpret_cast<const bf16x8_t*>(
                    wslice + (ct * 16 + l15) * CM + kb * 32 + g4 * 8);
            #pragma unroll
            for (int mt = 0; mt < 4; ++mt)
                #pragma unroll
                for (int ct = 0; ct < 2; ++ct)
                    acc2[wi][mt][ct] = mfma16(a[mt], b[ct], acc2[wi][mt][ct]);
        }
    }
    // scatter v transposed (b64 packed): v_sT[c][key]
    #pragma unroll
    for (int mt = 0; mt < 4; ++mt)
        #pragma unroll
        for (int ct = 0; ct < 2; ++ct)
            *reinterpret_cast<bf16x4_t*>(
                v_sT + (ct * 16 + l15) * VRW + w * 64 + mt * 16 + g4 * 4) =
                to_bf4(acc2[0][mt][ct]);
    // g = acc2[1] stays in registers
    __syncthreads();

    // hoist Q fragments (own 64 rows only)
    bf16x8_t qf[4];
    #pragma unroll
    for (int qt = 0; qt < 4; ++qt) {
        int row = w * 64 + qt * 16 + l15;
        qf[qt] = *reinterpret_cast<const bf16x8_t*>(kq_s + kq_addr(row, 4 + g4, 0));
    }

    float bgv[2];
    bgv[0] = bg[h * HC + l15];
    bgv[1] = bg[h * HC + 16 + l15];
    const float cs = 0.17677669529663687f * 1.4426950408889634f;  // scale * log2(e)

    int b5 = g4 >> 1;
    int src0 = l15 + 16 * ((2 * g4) & 3);      // source lane, frag elems j<4
    int src1 = l15 + 16 * ((2 * g4 + 1) & 3);  // source lane, frag elems j>=4

    __bf16* gor = go + (((size_t)r * NH + h) * NSEQ) * HC;

    #pragma unroll
    for (int qt = 0; qt < 4; ++qt) {
        // S^T = mfma(K, Q): lane (l15,g4) holds q=w*64+qt*16+l15, key=kt*16+g4*4+i
        f32x4_t sacc[16];
        #pragma unroll
        for (int kt = 0; kt < 16; ++kt) sacc[kt] = zf;
        #pragma unroll
        for (int kt = 0; kt < 16; ++kt) {
            int krow = kt * 16 + l15;
            bf16x8_t kfr = *reinterpret_cast<const bf16x8_t*>(kq_s + kq_addr(krow, g4, 0));
            sacc[kt] = mfma16(kfr, qf[qt], sacc[kt]);
        }

        // softmax over keys: 64 local values + xor16/xor32 reduce
        float mx = -1e30f;
        #pragma unroll
        for (int kt = 0; kt < 16; ++kt)
            #pragma unroll
            for (int i = 0; i < 4; ++i) mx = fmaxf(mx, sacc[kt][i]);
        mx = fmaxf(mx, __shfl_xor(mx, 16));
        mx = fmaxf(mx, __shfl_xor(mx, 32));
        float nmc = -mx * cs;
        float sum = 0.0f;
        #pragma unroll
        for (int kt = 0; kt < 16; ++kt)
            #pragma unroll
            for (int i = 0; i < 4; ++i) {
                float e = exp2f(__builtin_fmaf(sacc[kt][i], cs, nmc));
                sacc[kt][i] = e;
                sum += e;
            }
        sum += __shfl_xor(sum, 16);
        sum += __shfl_xor(sum, 32);
        float inv = 1.0f / sum;

        // pack normalized P into bf16 pairs: w01/w23[kt] = keys (4kt.. group g4)
        unsigned int w01[16], w23[16];
        #pragma unroll
        for (int kt = 0; kt < 16; ++kt) {
            w01[kt] = pkbf(sacc[kt][0] * inv, sacc[kt][1] * inv);
            w23[kt] = pkbf(sacc[kt][2] * inv, sacc[kt][3] * inv);
        }

        // PV with in-register P exchange: pa[kb] elem j comes from lane
        // (l15, (2*g4+(j>>2))&3), word kt=2kb+b5
        f32x4_t oacc[2];
        oacc[0] = zf; oacc[1] = zf;
        #pragma unroll
        for (int kb = 0; kb < 8; ++kb) {
            unsigned int u0a = __shfl((int)w01[2 * kb], src0), u0b = __shfl((int)w01[2 * kb + 1], src0);
            unsigned int u1a = __shfl((int)w23[2 * kb], src0), u1b = __shfl((int)w23[2 * kb + 1], src0);
            unsigned int u2a = __shfl((int)w01[2 * kb], src1), u2b = __shfl((int)w01[2 * kb + 1], src1);
            unsigned int u3a = __shfl((int)w23[2 * kb], src1), u3b = __shfl((int)w23[2 * kb + 1], src1);
            u32x4_t pw;
            pw[0] = b5 ? u0b : u0a;
            pw[1] = b5 ? u1b : u1a;
            pw[2] = b5 ? u2b : u2a;
            pw[3] = b5 ? u3b : u3a;
            bf16x8_t pa = __builtin_bit_cast(bf16x8_t, pw);
            #pragma unroll
            for (int ct = 0; ct < 2; ++ct) {
                bf16x8_t vb = *reinterpret_cast<const bf16x8_t*>(
                    v_sT + (ct * 16 + l15) * VRW + kb * 32 + g4 * 8);
                oacc[ct] = mfma16(pa, vb, oacc[ct]);
            }
        }

        // gated epilogue: g accumulator layout == o accumulator layout
        #pragma unroll
        for (int ct = 0; ct < 2; ++ct)
            #pragma unroll
            for (int i = 0; i < 4; ++i) {
                float t  = acc2[1][qt][ct][i] + bgv[ct];
                float gs = 1.0f / (1.0f + __expf(-t));
                int srow = w * 64 + qt * 16 + g4 * 4 + i;
                gor[(size_t)srow * HC + ct * 16 + l15] = (__bf16)(gs * oacc[ct][i]);
            }
    }
}

// ---------------- Kernel 4: out = (g*o) @ Wo + bo, scatter rows to (s,r) order ----------------
// go layout: [r][h][s][c]; k index kb*32+g4*8 maps to h=kb, c offset g4*8.
__global__ __launch_bounds__(256, 2) void outgemm_kernel(
        const __bf16* __restrict__ go, const __bf16* __restrict__ wto,
        const float* __restrict__ bo, float* __restrict__ out) {
    int tid = threadIdx.x, w = tid >> 6, lane = tid & 63;
    int l15 = lane & 15, g4 = lane >> 4;
    int j0 = blockIdx.x * 64 + w * 16;   // j = r*NSEQ + s; r uniform per block
    int rb = j0 >> 8;
    int s0 = j0 & (NSEQ - 1);
    const __bf16* gor = go + ((size_t)rb * NH) * NSEQ * HC;
    const f32x4_t zf = {0.0f, 0.0f, 0.0f, 0.0f};
    f32x4_t acc[16];
    #pragma unroll
    for (int nt = 0; nt < 16; ++nt) acc[nt] = zf;
    #pragma unroll
    for (int kb = 0; kb < 8; ++kb) {
        bf16x8_t a = *reinterpret_cast<const bf16x8_t*>(
            gor + ((size_t)kb * NSEQ + s0 + l15) * HC + g4 * 8);
        #pragma unroll
        for (int nt = 0; nt < 16; ++nt) {
            bf16x8_t b = *reinterpret_cast<const bf16x8_t*>(
                wto + (nt * 16 + l15) * CM + kb * 32 + g4 * 8);
            acc[nt] = mfma16(a, b, acc[nt]);
        }
    }
    #pragma unroll
    for (int nt = 0; nt < 16; ++nt) {
        float bias = bo[nt * 16 + l15];
        #pragma unroll
        for (int i = 0; i < 4; ++i) {
            int s = s0 + g4 * 4 + i;
            out[((size_t)(s * NRES + rb)) * CM + nt * 16 + l15] = acc[nt][i] + bias;
        }
    }
}

extern "C" void kernel_launch(void* const* d_in, const int* in_sizes, int n_in,
                              void* d_out, int out_size, void* d_ws, size_t ws_size,
                              hipStream_t stream) {
    const float* m     = (const float*)d_in[0];
    const float* gamma = (const float*)d_in[1];
    const float* beta  = (const float*)d_in[2];
    const float* wq    = (const float*)d_in[3];
    const float* wk    = (const float*)d_in[4];
    const float* wv    = (const float*)d_in[5];
    const float* wg    = (const float*)d_in[6];
    const float* bg    = (const float*)d_in[7];
    const float* wo    = (const float*)d_in[8];
    const float* bo    = (const float*)d_in[9];

    char* ws = (char*)d_ws;
    const size_t X_OFF  = 1u << 20;
    const size_t GO_OFF = X_OFF + (size_t)NRES * NSEQ * CM * 2;
    const size_t NEED   = GO_OFF + (size_t)NRES * NSEQ * CM * 2;
    if (ws_size < NEED) return;

    __bf16* wt = (__bf16*)ws;
    __bf16* x  = (__bf16*)(ws + X_OFF);
    __bf16* go = (__bf16*)(ws + GO_OFF);

    wprep_kernel<<<dim3(16, 5), 256, 0, stream>>>(wq, wk, wv, wg, wo, wt);
    ln_kernel<<<(NSEQ * NRES) / 4, 256, 0, stream>>>(m, gamma, beta, x);
    attn_kernel<<<NRES * NH, 256, 0, stream>>>(x, wt, bg, go);
    outgemm_kernel<<<(NRES * NSEQ) / 64, 256, 0, stream>>>(go, wt + 4 * (CM * CM), bo, (float*)d_out);
}